// Round 1
// baseline (88381.366 us; speedup 1.0000x reference)
//
#include <hip/hip_runtime.h>
#include <cstdio>
#include <cstdint>

// ---------------- problem constants ----------------
constexpr int SEQ   = 256;   // incoming seqlen
constexpr int BATCH = 64;
constexpr int HID   = 1024;  // I == H == P == 1024
constexpr int TH3   = 3072;  // 3*H
constexpr int PLEN  = 256;   // post seqlen
constexpr float NEGV = -1000000000.0f;

constexpr int NBLK = 256;
constexpr int NTHR = 256;

// ---------------- workspace layout (floats) ----------------
constexpr size_t OFF_H  = 1024;                                   // h state [64][1024]
constexpr size_t OFF_GP = OFF_H  + (size_t)BATCH * HID;           // g partials [16][64][3072]
constexpr size_t OFF_QP = OFF_GP + (size_t)16 * BATCH * TH3;      // q partials [8][64][1024]
constexpr size_t OFF_SC = OFF_QP + (size_t)8 * BATCH * HID;       // scores [2][64][256]
constexpr size_t OFF_MS = OFF_SC + (size_t)2 * BATCH * PLEN;      // chunk max [2][64][4]
constexpr size_t OFF_LS = OFF_MS + (size_t)2 * BATCH * 4;         // chunk sumexp [2][64][4]
constexpr size_t OFF_PC = OFF_LS + (size_t)2 * BATCH * 4;         // ctx partials [2][64][4][1024]
constexpr size_t WS_FLOATS = OFF_PC + (size_t)2 * BATCH * 4 * HID;

// ---------------- grid barrier (two-level, agent scope) ----------------
// bar[g*16] g=0..31 group counters (8 blocks/group), bar[512] root, bar[544] epoch
__device__ __forceinline__ void gbar(unsigned* bar) {
  __syncthreads();
  if (threadIdx.x == 0) {
    const unsigned e = __hip_atomic_load(&bar[544], __ATOMIC_RELAXED, __HIP_MEMORY_SCOPE_AGENT);
    __threadfence();
    const int g = blockIdx.x & 31;
    const unsigned o = __hip_atomic_fetch_add(&bar[g * 16], 1u, __ATOMIC_ACQ_REL, __HIP_MEMORY_SCOPE_AGENT);
    bool released = false;
    if (o == 7u) {
      const unsigned r = __hip_atomic_fetch_add(&bar[512], 1u, __ATOMIC_ACQ_REL, __HIP_MEMORY_SCOPE_AGENT);
      if (r == 31u) {
        #pragma unroll
        for (int i = 0; i < 32; ++i)
          __hip_atomic_store(&bar[i * 16], 0u, __ATOMIC_RELAXED, __HIP_MEMORY_SCOPE_AGENT);
        __hip_atomic_store(&bar[512], 0u, __ATOMIC_RELAXED, __HIP_MEMORY_SCOPE_AGENT);
        __hip_atomic_fetch_add(&bar[544], 1u, __ATOMIC_RELEASE, __HIP_MEMORY_SCOPE_AGENT);
        released = true;
      }
    }
    if (!released) {
      while (__hip_atomic_load(&bar[544], __ATOMIC_ACQUIRE, __HIP_MEMORY_SCOPE_AGENT) == e)
        __builtin_amdgcn_s_sleep(1);
    }
    __threadfence();
  }
  __syncthreads();
}

// ---------------- S1 tile GEMM: out[64][*] partial = A[64][1024] (cols c0..) ----------------
// K-chunk of 128 at offset k0. CPT=8 -> 256 cols/WG, CPT=4 -> 128 cols/WG.
// LDS: As[32][64] (k-major), Ws[32][CCNT] (k-major). Per-thread 8b x CPTc regs,
// columns interleaved stride 32 so compute-phase LDS reads are conflict-free.
template <int CPT>
__device__ __forceinline__ void s1_gemm(
    const float* __restrict__ A, const float* __restrict__ Wr,
    float* __restrict__ outp, int out_stride, int c0, int k0,
    float* __restrict__ As, float* __restrict__ Ws)
{
  constexpr int CCNT = CPT * 32;
  const int tid = threadIdx.x;
  const int bi = tid >> 5, ci = tid & 31;
  float acc[8][CPT];
#pragma unroll
  for (int i = 0; i < 8; ++i)
#pragma unroll
    for (int j = 0; j < CPT; ++j) acc[i][j] = 0.f;

  for (int t = 0; t < 4; ++t) {
    const int kb = k0 + t * 32;
    {  // stage A (transpose to k-major): 64 rows x 32 k
      const int b = tid & 63, kq = tid >> 6;  // kq 0..3
      const float* src = A + (size_t)b * 1024 + kb;
      const float4 v0 = *(const float4*)(src + kq * 4);
      const float4 v1 = *(const float4*)(src + 16 + kq * 4);
      const int k4 = kq * 4;
      As[(k4 + 0) * 64 + b] = v0.x;
      As[(k4 + 1) * 64 + b] = v0.y;
      As[(k4 + 2) * 64 + b] = v0.z;
      As[(k4 + 3) * 64 + b] = v0.w;
      As[(k4 + 16) * 64 + b] = v1.x;
      As[(k4 + 17) * 64 + b] = v1.y;
      As[(k4 + 18) * 64 + b] = v1.z;
      As[(k4 + 19) * 64 + b] = v1.w;
    }
    if (CPT == 8) {  // stage W: 256 rows x 32 k
      const int c = tid;
      const float* src = Wr + (size_t)(c0 + c) * 1024 + kb;
#pragma unroll
      for (int f = 0; f < 8; ++f) {
        const float4 v = *(const float4*)(src + f * 4);
        Ws[(f * 4 + 0) * CCNT + c] = v.x;
        Ws[(f * 4 + 1) * CCNT + c] = v.y;
        Ws[(f * 4 + 2) * CCNT + c] = v.z;
        Ws[(f * 4 + 3) * CCNT + c] = v.w;
      }
    } else {  // 128 rows x 32 k
      const int c = tid & 127, fh = tid >> 7;
      const float* src = Wr + (size_t)(c0 + c) * 1024 + kb;
#pragma unroll
      for (int f2 = 0; f2 < 4; ++f2) {
        const int f = fh * 4 + f2;
        const float4 v = *(const float4*)(src + f * 4);
        Ws[(f * 4 + 0) * CCNT + c] = v.x;
        Ws[(f * 4 + 1) * CCNT + c] = v.y;
        Ws[(f * 4 + 2) * CCNT + c] = v.z;
        Ws[(f * 4 + 3) * CCNT + c] = v.w;
      }
    }
    __syncthreads();
#pragma unroll 4
    for (int k = 0; k < 32; ++k) {
      const float4 a0 = *(const float4*)&As[k * 64 + bi * 8];
      const float4 a1 = *(const float4*)&As[k * 64 + bi * 8 + 4];
      const float a[8] = {a0.x, a0.y, a0.z, a0.w, a1.x, a1.y, a1.z, a1.w};
      float w[CPT];
#pragma unroll
      for (int j = 0; j < CPT; ++j) w[j] = Ws[k * CCNT + j * 32 + ci];
#pragma unroll
      for (int i = 0; i < 8; ++i)
#pragma unroll
        for (int j = 0; j < CPT; ++j) acc[i][j] = fmaf(a[i], w[j], acc[i][j]);
    }
    __syncthreads();
  }
#pragma unroll
  for (int i = 0; i < 8; ++i) {
    const int b = bi * 8 + i;
#pragma unroll
    for (int j = 0; j < CPT; ++j)
      outp[(size_t)b * out_stride + c0 + j * 32 + ci] = acc[i][j];
  }
}

// ---------------- the persistent kernel ----------------
__global__ __launch_bounds__(NTHR)
void gru_attn_kernel(const float* __restrict__ incoming, const float* __restrict__ post,
                     const float* __restrict__ h_init, const float* __restrict__ W_ih,
                     const float* __restrict__ W_hh, const float* __restrict__ b_ih,
                     const float* __restrict__ b_hh, const float* __restrict__ Wq,
                     const float* __restrict__ bq, const int* __restrict__ length,
                     const int* __restrict__ post_length,
                     float* __restrict__ out, float* __restrict__ ws)
{
  __shared__ float lds[10240];          // 40 KB
  float* As = lds;                      // [32][64]
  float* Ws = lds + 2048;               // [32][<=256]
  float* qs = lds;                      // attention: q reduced [1024]
  float* scloc = lds + 1024;            // [64]
  float* wloc = lds + 1088;             // [64]

  unsigned* bar = (unsigned*)ws;
  float* h = ws + OFF_H;
  float* out_hs   = out + (size_t)BATCH * HID;
  float* out_attn = out_hs + (size_t)SEQ * BATCH * 2048;

  const int bid = blockIdx.x, tid = threadIdx.x;

  // init h = broadcast h_init
  {
    const int idx = bid * NTHR + tid;
    h[idx] = h_init[idx & (HID - 1)];
  }
  gbar(bar);

  for (int s = 0; s <= SEQ + 1; ++s) {
    // ---------------- segment 1: GEMMs ----------------
    if (bid < 192) {
      if (s < SEQ) {  // g(s) = x(s)@W_ih^T + h@W_hh^T (partials; biases later)
        const int ks = bid & 15, cg = bid >> 4;
        const float* A  = (ks < 8) ? (incoming + (size_t)s * BATCH * HID) : h;
        const float* Wr = (ks < 8) ? W_ih : W_hh;
        const int k0 = (ks & 7) * 128;
        s1_gemm<8>(A, Wr, ws + OFF_GP + (size_t)ks * BATCH * TH3, TH3, cg * 256, k0, As, Ws);
      }
    } else {
      if (s >= 1 && s <= SEQ) {  // q(s-1) = h@Wq^T (partials)
        const int idx = bid - 192, ks = idx & 7, cg = idx >> 3;
        s1_gemm<4>(h, Wq, ws + OFF_QP + (size_t)ks * BATCH * HID, HID, cg * 128, ks * 128, As, Ws);
      }
    }
    gbar(bar);

    // ---------------- segment 2 ----------------
    // (a) gates -> h_new(s), in place; write hs h-part
    if (s < SEQ) {
      const int idx = bid * NTHR + tid;
      const int b = idx >> 10, j = idx & 1023;
      float sx_r = b_ih[j], sx_z = b_ih[j + 1024], sx_n = b_ih[j + 2048];
      float sh_r = b_hh[j], sh_z = b_hh[j + 1024], sh_n = b_hh[j + 2048];
#pragma unroll
      for (int ks = 0; ks < 8; ++ks) {
        const float* gb = ws + OFF_GP + (size_t)ks * BATCH * TH3 + (size_t)b * TH3;
        sx_r += gb[j]; sx_z += gb[j + 1024]; sx_n += gb[j + 2048];
      }
#pragma unroll
      for (int ks = 8; ks < 16; ++ks) {
        const float* gb = ws + OFF_GP + (size_t)ks * BATCH * TH3 + (size_t)b * TH3;
        sh_r += gb[j]; sh_z += gb[j + 1024]; sh_n += gb[j + 2048];
      }
      const float r = 1.f / (1.f + expf(-(sx_r + sh_r)));
      const float z = 1.f / (1.f + expf(-(sx_z + sh_z)));
      const float n = tanhf(sx_n + r * sh_n);
      const float hold = h[idx];
      const float keep = (s < length[b]) ? 1.f : 0.f;
      const float hn = (n + z * (hold - n)) * keep;
      h[idx] = hn;
      out_hs[(size_t)s * (BATCH * 2048) + (size_t)b * 2048 + j] = hn;
    }

    // (b) attention pass for step s-1: scores + chunk-local softmax + ctx partial
    if (s >= 1 && s <= SEQ) {
      const int sm1 = s - 1, buf = sm1 & 1;
      const int b = bid >> 2, lc = bid & 3, l0 = lc * 64;
      const int plen = post_length[b];
      {  // reduce q partials (+bq) into LDS
        float4 qv = *(const float4*)&bq[tid * 4];
#pragma unroll
        for (int ks = 0; ks < 8; ++ks) {
          const float4 v = *(const float4*)&ws[OFF_QP + (size_t)ks * BATCH * HID + (size_t)b * HID + tid * 4];
          qv.x += v.x; qv.y += v.y; qv.z += v.z; qv.w += v.w;
        }
        ((float4*)qs)[tid] = qv;
      }
      __syncthreads();
      {  // scores: 4 waves x 16 l each
        const int wv = tid >> 6, lane = tid & 63;
        float* scb = ws + OFF_SC + (size_t)buf * (BATCH * PLEN) + (size_t)b * PLEN;
        for (int i = 0; i < 16; ++i) {
          const int l = l0 + wv * 16 + i;
          float sc;
          if (l < plen) {
            const float* prow = post + (size_t)l * (BATCH * HID) + (size_t)b * HID;
            sc = 0.f;
#pragma unroll
            for (int u = 0; u < 16; ++u) {
              const int p = u * 64 + lane;
              sc = fmaf(qs[p], prow[p], sc);
            }
#pragma unroll
            for (int off = 32; off > 0; off >>= 1) sc += __shfl_xor(sc, off);
          } else {
            sc = NEGV;
          }
          if (lane == 0) { scloc[wv * 16 + i] = sc; scb[l] = sc; }
        }
      }
      __syncthreads();
      if (tid < 64) {  // chunk-local softmax stats
        const float v = scloc[tid];
        float m = v;
#pragma unroll
        for (int off = 32; off > 0; off >>= 1) m = fmaxf(m, __shfl_xor(m, off));
        const float w = expf(v - m);
        float lsum = w;
#pragma unroll
        for (int off = 32; off > 0; off >>= 1) lsum += __shfl_xor(lsum, off);
        wloc[tid] = w;
        if (tid == 0) {
          ws[OFF_MS + (size_t)buf * (BATCH * 4) + b * 4 + lc] = m;
          ws[OFF_LS + (size_t)buf * (BATCH * 4) + b * 4 + lc] = lsum;
        }
      }
      __syncthreads();
      {  // ctx partial (skip fully-masked tail rows: their weight is exactly 0)
        float4 cp = {0.f, 0.f, 0.f, 0.f};
        const int p0 = tid * 4;
        const int lmax = (plen - l0 < 64) ? (plen - l0) : 64;
        for (int l = 0; l < lmax; ++l) {
          const float w = wloc[l];
          const float4 pv = *(const float4*)&post[(size_t)(l0 + l) * (BATCH * HID) + (size_t)b * HID + p0];
          cp.x = fmaf(w, pv.x, cp.x);
          cp.y = fmaf(w, pv.y, cp.y);
          cp.z = fmaf(w, pv.z, cp.z);
          cp.w = fmaf(w, pv.w, cp.w);
        }
        *(float4*)&ws[OFF_PC + (size_t)buf * (BATCH * 4 * HID) + (size_t)b * (4 * HID) + (size_t)lc * HID + p0] = cp;
      }
    }

    // (c) combine chunks for step s-2: context + attn outputs
    if (s >= 2) {
      const int s2 = s - 2, buf2 = s2 & 1;
      {  // context -> hs[s2][b][1024+p]
        const int b = bid >> 2, pq = bid & 3;
        const float* msv = ws + OFF_MS + (size_t)buf2 * (BATCH * 4) + b * 4;
        const float* lsv = ws + OFF_LS + (size_t)buf2 * (BATCH * 4) + b * 4;
        const float m0 = msv[0], m1 = msv[1], m2 = msv[2], m3 = msv[3];
        const float mg = fmaxf(fmaxf(m0, m1), fmaxf(m2, m3));
        const float w0 = expf(m0 - mg), w1 = expf(m1 - mg), w2 = expf(m2 - mg), w3 = expf(m3 - mg);
        const float lg = lsv[0] * w0 + lsv[1] * w1 + lsv[2] * w2 + lsv[3] * w3;
        const float inv = 1.f / lg;
        const int p = pq * 256 + tid;
        const float* pcb = ws + OFF_PC + (size_t)buf2 * (BATCH * 4 * HID) + (size_t)b * (4 * HID);
        const float ctx = (pcb[p] * w0 + pcb[HID + p] * w1 + pcb[2 * HID + p] * w2 + pcb[3 * HID + p] * w3) * inv;
        out_hs[(size_t)s2 * (BATCH * 2048) + (size_t)b * 2048 + 1024 + p] = ctx;
      }
      if (tid < 64) {  // attn[s2][l=bid][b=tid]
        const int l = bid, b = tid;
        const float* msv = ws + OFF_MS + (size_t)buf2 * (BATCH * 4) + b * 4;
        const float* lsv = ws + OFF_LS + (size_t)buf2 * (BATCH * 4) + b * 4;
        const float m0 = msv[0], m1 = msv[1], m2 = msv[2], m3 = msv[3];
        const float mg = fmaxf(fmaxf(m0, m1), fmaxf(m2, m3));
        const float lg = lsv[0] * expf(m0 - mg) + lsv[1] * expf(m1 - mg) +
                         lsv[2] * expf(m2 - mg) + lsv[3] * expf(m3 - mg);
        const float sc = ws[OFF_SC + (size_t)buf2 * (BATCH * PLEN) + (size_t)b * PLEN + l];
        out_attn[(size_t)s2 * (PLEN * BATCH) + (size_t)l * BATCH + b] = expf(sc - mg) / lg;
      }
    }
    gbar(bar);
  }

  // epilogue: h_last
  {
    const int idx = bid * NTHR + tid;
    out[idx] = h[idx];
  }
}

// ---------------- host ----------------
extern "C" void kernel_launch(void* const* d_in, const int* in_sizes, int n_in,
                              void* d_out, int out_size, void* d_ws, size_t ws_size,
                              hipStream_t stream) {
  const float* incoming   = (const float*)d_in[0];
  const float* post       = (const float*)d_in[1];
  const float* h_init     = (const float*)d_in[2];
  const float* W_ih       = (const float*)d_in[3];
  const float* W_hh       = (const float*)d_in[4];
  const float* b_ih       = (const float*)d_in[5];
  const float* b_hh       = (const float*)d_in[6];
  const float* Wq         = (const float*)d_in[7];
  const float* bq         = (const float*)d_in[8];
  const int*   length     = (const int*)d_in[9];
  const int*   post_length= (const int*)d_in[10];
  float* out = (float*)d_out;
  float* ws  = (float*)d_ws;

  fprintf(stderr, "[gru_attn] ws_size=%zu bytes, need=%zu bytes, out_size=%d, n_in=%d\n",
          ws_size, WS_FLOATS * sizeof(float), out_size, n_in);
  if (ws_size < WS_FLOATS * sizeof(float)) {
    fprintf(stderr, "[gru_attn] ERROR: workspace too small!\n");
    return;
  }

  // zero the barrier region (ws is poisoned 0xAA before every launch)
  hipMemsetAsync(d_ws, 0, 4096, stream);
  hipLaunchKernelGGL(gru_attn_kernel, dim3(NBLK), dim3(NTHR), 0, stream,
                     incoming, post, h_init, W_ih, W_hh, b_ih, b_hh, Wq, bq,
                     length, post_length, out, ws);
}

// Round 2
// 11407.510 us; speedup vs baseline: 7.7476x; 7.7476x over previous
//
#include <hip/hip_runtime.h>
#include <cstdio>
#include <cstdint>
#include <math.h>

typedef float vf4 __attribute__((ext_vector_type(4)));

// ---------------- problem constants ----------------
constexpr int SEQ = 256, BATCH = 64, HID = 1024, TH3 = 3072, PLEN = 256;
constexpr float NEGV = -1000000000.0f;

constexpr int GI_CHUNK = 16;   // steps of gi precompute per chunk (ws-bounded)
constexpr int Q_CHUNK  = 32;   // steps per q/attention chunk

// ---------------- workspace layout (floats) ----------------
constexpr size_t OFF_H   = 1024;                    // barrier region = 4 KB
constexpr size_t OFF_SCR = OFF_H + 2 * 1024 * 64;   // h_T double buffer [2][1024][64]
constexpr size_t SCR_FLOATS = (size_t)GI_CHUNK * TH3 * BATCH;  // 3,145,728 (Q2 chunk 2,097,152 fits too)
constexpr size_t WS_NEED = (OFF_SCR + SCR_FLOATS) * sizeof(float);  // ~13.1 MB

// ---------------- grid barrier: relaxed spin, one acquire ----------------
__device__ __forceinline__ void gbar(unsigned* bar) {
  __syncthreads();
  if (threadIdx.x == 0) {
    const unsigned e = __hip_atomic_load(&bar[544], __ATOMIC_RELAXED, __HIP_MEMORY_SCOPE_AGENT);
    const int g = blockIdx.x & 31;
    const unsigned o = __hip_atomic_fetch_add(&bar[g * 16], 1u, __ATOMIC_ACQ_REL, __HIP_MEMORY_SCOPE_AGENT);
    bool last = false;
    if (o == 7u) {
      const unsigned r = __hip_atomic_fetch_add(&bar[512], 1u, __ATOMIC_ACQ_REL, __HIP_MEMORY_SCOPE_AGENT);
      if (r == 31u) {
#pragma unroll
        for (int i = 0; i < 32; ++i)
          __hip_atomic_store(&bar[i * 16], 0u, __ATOMIC_RELAXED, __HIP_MEMORY_SCOPE_AGENT);
        __hip_atomic_store(&bar[512], 0u, __ATOMIC_RELAXED, __HIP_MEMORY_SCOPE_AGENT);
        __hip_atomic_fetch_add(&bar[544], 1u, __ATOMIC_RELEASE, __HIP_MEMORY_SCOPE_AGENT);
        last = true;
      }
    }
    if (!last) {
      while (__hip_atomic_load(&bar[544], __ATOMIC_RELAXED, __HIP_MEMORY_SCOPE_AGENT) == e)
        __builtin_amdgcn_s_sleep(8);
    }
    (void)__hip_atomic_load(&bar[544], __ATOMIC_ACQUIRE, __HIP_MEMORY_SCOPE_AGENT);  // one buffer_inv
  }
  __syncthreads();
}

// ---------------- P1: gi[sl][row][b] = X[s]@W_ih^T + b_ih ----------------
__global__ __launch_bounds__(256)
void k_gi(const float* __restrict__ X, const float* __restrict__ W,
          const float* __restrict__ bias, float* __restrict__ gi, int s0)
{
  __shared__ float Wt[32 * 128];  // [kk][row]
  __shared__ float Xs[32 * 64];   // [kk][b]
  const int rt = blockIdx.x;      // 24 row tiles of 128
  const int sl = blockIdx.y;      // step within chunk
  const int s = s0 + sl;
  const int tid = threadIdx.x;
  const int mq = tid & 31, bq = tid >> 5;   // thread: rows {mq+32j}, b {bq*8..+7}
  const int m0 = rt * 128;
  const float* Xg = X + (size_t)s * (BATCH * HID);
  float acc[4][8];
#pragma unroll
  for (int j = 0; j < 4; ++j)
#pragma unroll
    for (int i = 0; i < 8; ++i) acc[j][i] = 0.f;

  for (int kt = 0; kt < 32; ++kt) {
    const int k0 = kt * 32;
    {  // stage W tile: 128 rows x 32 k, coalesced (2 threads per row)
      const int row = tid >> 1, half = tid & 1;
      const float* srcp = W + (size_t)(m0 + row) * HID + k0 + half * 16;
#pragma unroll
      for (int f = 0; f < 4; ++f) {
        vf4 v = *(const vf4*)(srcp + f * 4);
        const int kb = half * 16 + f * 4;
        Wt[(kb + 0) * 128 + row] = v[0];
        Wt[(kb + 1) * 128 + row] = v[1];
        Wt[(kb + 2) * 128 + row] = v[2];
        Wt[(kb + 3) * 128 + row] = v[3];
      }
    }
    {  // stage X tile: 64 b x 32 k
      const int b = tid >> 2, kq = tid & 3;  // f4 slots {kq, kq+4}
      const float* srcp = Xg + (size_t)b * HID + k0;
#pragma unroll
      for (int hh = 0; hh < 2; ++hh) {
        const int slot = kq + hh * 4;
        vf4 v = *(const vf4*)(srcp + slot * 4);
        Xs[(slot * 4 + 0) * 64 + b] = v[0];
        Xs[(slot * 4 + 1) * 64 + b] = v[1];
        Xs[(slot * 4 + 2) * 64 + b] = v[2];
        Xs[(slot * 4 + 3) * 64 + b] = v[3];
      }
    }
    __syncthreads();
#pragma unroll 4
    for (int kk = 0; kk < 32; ++kk) {
      vf4 x0 = *(const vf4*)&Xs[kk * 64 + bq * 8];
      vf4 x1 = *(const vf4*)&Xs[kk * 64 + bq * 8 + 4];
      float wv[4];
#pragma unroll
      for (int jj = 0; jj < 4; ++jj) wv[jj] = Wt[kk * 128 + mq + 32 * jj];
#pragma unroll
      for (int jj = 0; jj < 4; ++jj) {
        acc[jj][0] = fmaf(wv[jj], x0[0], acc[jj][0]);
        acc[jj][1] = fmaf(wv[jj], x0[1], acc[jj][1]);
        acc[jj][2] = fmaf(wv[jj], x0[2], acc[jj][2]);
        acc[jj][3] = fmaf(wv[jj], x0[3], acc[jj][3]);
        acc[jj][4] = fmaf(wv[jj], x1[0], acc[jj][4]);
        acc[jj][5] = fmaf(wv[jj], x1[1], acc[jj][5]);
        acc[jj][6] = fmaf(wv[jj], x1[2], acc[jj][6]);
        acc[jj][7] = fmaf(wv[jj], x1[3], acc[jj][7]);
      }
    }
    __syncthreads();
  }
#pragma unroll
  for (int jj = 0; jj < 4; ++jj) {
    const int m = m0 + mq + 32 * jj;
    const float bm = bias[m];
    float* dst = gi + (size_t)sl * (TH3 * 64) + (size_t)m * 64 + bq * 8;
    vf4 o0 = {acc[jj][0] + bm, acc[jj][1] + bm, acc[jj][2] + bm, acc[jj][3] + bm};
    vf4 o1 = {acc[jj][4] + bm, acc[jj][5] + bm, acc[jj][6] + bm, acc[jj][7] + bm};
    *(vf4*)dst = o0;
    *(vf4*)(dst + 4) = o1;
  }
}

// ---------------- P2: sequential GRU recurrence, W_hh LDS-resident ----------------
__global__ __launch_bounds__(256)
void k_rec(const float* __restrict__ gi, const float* __restrict__ W_hh,
           const float* __restrict__ b_hh, const int* __restrict__ length,
           const float* __restrict__ h_init, float* __restrict__ out,
           float* __restrict__ ws, int s0, int last_chunk)
{
  __shared__ float lds[16384];   // 64 KB: Wl[12][1024] + hs[4096]
  float* Wl = lds;
  float* hs = lds + 12288;
  unsigned* bar = (unsigned*)ws;
  const int wg = blockIdx.x, tid = threadIdx.x;
  const int wave = tid >> 6, lane = tid & 63;
  float* out_hs = out + (size_t)BATCH * HID;

  // load the WG's 12 W_hh rows into LDS once (rows g*1024 + wg*4 + c)
  for (int t = tid; t < 3072; t += 256) {   // f4 index: 12 rows * 256 f4
    const int r = t >> 8, kq = t & 255;
    const int grow = (r >> 2) * 1024 + wg * 4 + (r & 3);
    *(vf4*)&Wl[r * 1024 + kq * 4] = *(const vf4*)&W_hh[(size_t)grow * HID + kq * 4];
  }
  const int lb = length[lane];
  const float bh0 = b_hh[0 * 1024 + wg * 4 + wave];
  const float bh1 = b_hh[1 * 1024 + wg * 4 + wave];
  const float bh2 = b_hh[2 * 1024 + wg * 4 + wave];
  if (s0 == 0) {  // init transposed h state
    const int j = wg * 4 + wave;
    (ws + OFF_H)[j * 64 + lane] = h_init[j];
  }
  gbar(bar);

  for (int s = s0; s < s0 + GI_CHUNK; ++s) {
    const float* hT = ws + OFF_H + (size_t)(s & 1) * 65536;
    float* hTn = ws + OFF_H + (size_t)((s + 1) & 1) * 65536;
    float acc[12];
#pragma unroll
    for (int r = 0; r < 12; ++r) acc[r] = 0.f;

    vf4 rbuf[4];
    {
      const vf4* src = (const vf4*)hT;
#pragma unroll
      for (int j = 0; j < 4; ++j) rbuf[j] = src[tid + 256 * j];
    }
    for (int kt = 0; kt < 16; ++kt) {
      vf4* dst = (vf4*)hs;
#pragma unroll
      for (int j = 0; j < 4; ++j) dst[tid + 256 * j] = rbuf[j];
      __syncthreads();
      if (kt < 15) {  // prefetch next tile during compute
        const vf4* src = (const vf4*)(hT + (kt + 1) * 4096);
#pragma unroll
        for (int j = 0; j < 4; ++j) rbuf[j] = src[tid + 256 * j];
      }
#pragma unroll
      for (int kq = 0; kq < 4; ++kq) {
        const int kk = wave * 16 + kq * 4;
        vf4 wv[12];
#pragma unroll
        for (int r = 0; r < 12; ++r)
          wv[r] = *(const vf4*)&Wl[r * 1024 + kt * 64 + kk];
        float hv[4];
#pragma unroll
        for (int i = 0; i < 4; ++i) hv[i] = hs[(kk + i) * 64 + lane];
#pragma unroll
        for (int i = 0; i < 4; ++i) {
          const float hvi = hv[i];
#pragma unroll
          for (int r = 0; r < 12; ++r) acc[r] = fmaf(hvi, wv[r][i], acc[r]);
        }
      }
      __syncthreads();
    }
    // cross-wave k-reduction
#pragma unroll
    for (int r = 0; r < 12; ++r) hs[wave * 768 + r * 64 + lane] = acc[r];
    __syncthreads();
    // gates: thread = (col c = wave, batch b = lane)
    const int j = wg * 4 + wave;
    float gsum[3];
#pragma unroll
    for (int g = 0; g < 3; ++g) {
      const int r = g * 4 + wave;
      gsum[g] = hs[r * 64 + lane] + hs[768 + r * 64 + lane] +
                hs[1536 + r * 64 + lane] + hs[2304 + r * 64 + lane];
    }
    const size_t gib = (size_t)(s - s0) * (TH3 * 64);
    const float gi_r = gi[gib + (size_t)(0 * 1024 + j) * 64 + lane];
    const float gi_z = gi[gib + (size_t)(1 * 1024 + j) * 64 + lane];
    const float gi_n = gi[gib + (size_t)(2 * 1024 + j) * 64 + lane];
    const float rg = 1.f / (1.f + expf(-(gi_r + gsum[0] + bh0)));
    const float zg = 1.f / (1.f + expf(-(gi_z + gsum[1] + bh1)));
    const float ng = tanhf(gi_n + rg * (gsum[2] + bh2));
    const float hold = hT[j * 64 + lane];
    const float keep = (s < lb) ? 1.f : 0.f;
    const float hn = (ng + zg * (hold - ng)) * keep;
    hTn[j * 64 + lane] = hn;                 // coalesced transposed state
    hs[3328 + lane * 4 + wave] = hn;         // for f4-coalesced out_hs write
    __syncthreads();
    if (tid < 64)
      *(vf4*)&out_hs[(size_t)s * (BATCH * 2048) + (size_t)tid * 2048 + wg * 4] =
          *(vf4*)&hs[3328 + tid * 4];
    gbar(bar);
  }
  if (last_chunk) {  // h_last: buffer (s0+16)&1 == 0 holds h(255)
    const float* hf = ws + OFF_H;
    const int j = wg * 4 + wave;
    out[(size_t)lane * HID + j] = hf[j * 64 + lane];
  }
}

// ---------------- P3: Q2[b][sl][p] = H[s][b][:]@Wq^T + bq ----------------
__global__ __launch_bounds__(256)
void k_q(const float* __restrict__ Hbase, const float* __restrict__ Wq,
         const float* __restrict__ bq, float* __restrict__ Q2, int s0)
{
  __shared__ float Wt[32 * 128];  // [kk][p]
  __shared__ float Ht[32 * 32];   // [kk][sl]
  const int pt = blockIdx.x;      // 8 p tiles
  const int b = blockIdx.y;       // 64
  const int tid = threadIdx.x;
  const int pq = tid & 31;        // p = p0 + pq*4..+3
  const int sq = tid >> 5;        // sl = sq*4..+3
  const int p0 = pt * 128;
  float acc[4][4];  // [sl][p]
#pragma unroll
  for (int i = 0; i < 4; ++i)
#pragma unroll
    for (int jj = 0; jj < 4; ++jj) acc[i][jj] = 0.f;

  for (int kt = 0; kt < 32; ++kt) {
    const int k0 = kt * 32;
    {  // stage Wq tile (same pattern as k_gi)
      const int row = tid >> 1, half = tid & 1;
      const float* srcp = Wq + (size_t)(p0 + row) * HID + k0 + half * 16;
#pragma unroll
      for (int f = 0; f < 4; ++f) {
        vf4 v = *(const vf4*)(srcp + f * 4);
        const int kb = half * 16 + f * 4;
        Wt[(kb + 0) * 128 + row] = v[0];
        Wt[(kb + 1) * 128 + row] = v[1];
        Wt[(kb + 2) * 128 + row] = v[2];
        Wt[(kb + 3) * 128 + row] = v[3];
      }
    }
    {  // stage H tile: 32 sl x 32 k (rows stride 2048 within batch b)
      const int sl = tid >> 3, slot = tid & 7;
      vf4 v = *(const vf4*)&Hbase[(size_t)(s0 + sl) * (BATCH * 2048) + (size_t)b * 2048 + k0 + slot * 4];
      Ht[(slot * 4 + 0) * 32 + sl] = v[0];
      Ht[(slot * 4 + 1) * 32 + sl] = v[1];
      Ht[(slot * 4 + 2) * 32 + sl] = v[2];
      Ht[(slot * 4 + 3) * 32 + sl] = v[3];
    }
    __syncthreads();
#pragma unroll 4
    for (int kk = 0; kk < 32; ++kk) {
      vf4 hv = *(const vf4*)&Ht[kk * 32 + sq * 4];
      vf4 wv = *(const vf4*)&Wt[kk * 128 + pq * 4];
#pragma unroll
      for (int si = 0; si < 4; ++si)
#pragma unroll
        for (int pi = 0; pi < 4; ++pi) acc[si][pi] = fmaf(hv[si], wv[pi], acc[si][pi]);
    }
    __syncthreads();
  }
  vf4 bqv = *(const vf4*)&bq[p0 + pq * 4];
#pragma unroll
  for (int si = 0; si < 4; ++si) {
    vf4 o = {acc[si][0] + bqv[0], acc[si][1] + bqv[1], acc[si][2] + bqv[2], acc[si][3] + bqv[3]};
    *(vf4*)&Q2[(size_t)b * (Q_CHUNK * 1024) + (size_t)(sq * 4 + si) * 1024 + p0 + pq * 4] = o;
  }
}

// ---------------- P4: scores -> softmax -> context + attn out ----------------
__global__ __launch_bounds__(256)
void k_attn(const float* __restrict__ post, const float* __restrict__ Q2,
            const int* __restrict__ post_length, float* __restrict__ out, int s0)
{
  __shared__ float q8[8 * 1024];   // 32 KB
  __shared__ float Pt[32 * 132];   // 16.5 KB (pad 132 for conflict-free b128)
  __shared__ float sc[8 * 256];    // 8 KB
  __shared__ float stat[8];
  const int b = blockIdx.x, st = blockIdx.y;
  const int tid = threadIdx.x, wave = tid >> 6, lane = tid & 63;
  const int plen = post_length[b];
  const int sbase = s0 + st * 8;
  float* out_hs = out + (size_t)BATCH * HID;
  float* out_attn = out_hs + (size_t)SEQ * BATCH * 2048;

  {  // load 8 query rows
    const vf4* src = (const vf4*)(Q2 + (size_t)b * (Q_CHUNK * 1024) + (size_t)st * 8 * 1024);
    vf4* dst = (vf4*)q8;
#pragma unroll
    for (int i = 0; i < 8; ++i) dst[tid + 256 * i] = src[tid + 256 * i];
  }
  __syncthreads();

  // scores: thread = (l = l0 + tid&31, s = tid>>5)
  const int l32 = tid & 31, sq = tid >> 5;
  for (int lt = 0; lt < 8; ++lt) {
    const int l0 = lt * 32;
    if (l0 < plen) {  // WG-uniform branch
      float a = 0.f;
      for (int ptile = 0; ptile < 8; ++ptile) {
#pragma unroll
        for (int i = 0; i < 4; ++i) {
          const int f4i = tid + 256 * i;
          const int row = f4i >> 5, c4 = f4i & 31;
          *(vf4*)&Pt[row * 132 + c4 * 4] =
              *(const vf4*)&post[(size_t)(l0 + row) * (BATCH * HID) + (size_t)b * HID + ptile * 128 + c4 * 4];
        }
        __syncthreads();
#pragma unroll 8
        for (int p4 = 0; p4 < 32; ++p4) {
          vf4 qv = *(const vf4*)&q8[sq * 1024 + ptile * 128 + p4 * 4];
          vf4 pv = *(const vf4*)&Pt[l32 * 132 + p4 * 4];
          a = fmaf(qv[0], pv[0], a);
          a = fmaf(qv[1], pv[1], a);
          a = fmaf(qv[2], pv[2], a);
          a = fmaf(qv[3], pv[3], a);
        }
        __syncthreads();
      }
      sc[sq * 256 + l0 + l32] = (l0 + l32 < plen) ? a : NEGV;
    } else {
      sc[sq * 256 + l0 + l32] = NEGV;
    }
  }
  __syncthreads();

  // softmax per s over l (wave handles s = wave, wave+4)
  for (int si = wave; si < 8; si += 4) {
    float v0 = sc[si * 256 + lane], v1 = sc[si * 256 + 64 + lane];
    float v2 = sc[si * 256 + 128 + lane], v3 = sc[si * 256 + 192 + lane];
    float m = fmaxf(fmaxf(v0, v1), fmaxf(v2, v3));
#pragma unroll
    for (int off = 32; off > 0; off >>= 1) m = fmaxf(m, __shfl_xor(m, off));
    float e0 = expf(v0 - m), e1 = expf(v1 - m), e2 = expf(v2 - m), e3 = expf(v3 - m);
    float ssum = e0 + e1 + e2 + e3;
#pragma unroll
    for (int off = 32; off > 0; off >>= 1) ssum += __shfl_xor(ssum, off);
    sc[si * 256 + lane] = e0;
    sc[si * 256 + 64 + lane] = e1;
    sc[si * 256 + 128 + lane] = e2;
    sc[si * 256 + 192 + lane] = e3;
    if (lane == 0) stat[si] = 1.f / ssum;
  }
  __syncthreads();

  // attn weights out: [s][l][b]
#pragma unroll
  for (int i = 0; i < 8; ++i) {
    const int idx = tid + 256 * i;
    const int si = idx >> 8, l = idx & 255;
    out_attn[(size_t)(sbase + si) * (PLEN * BATCH) + (size_t)l * BATCH + b] = sc[si * 256 + l] * stat[si];
  }

  // context: thread owns p4 = tid*4, all 8 s
  vf4 a[8];
#pragma unroll
  for (int s8 = 0; s8 < 8; ++s8) a[s8] = (vf4){0.f, 0.f, 0.f, 0.f};
  const int lr = (plen + 3) & ~3;
  for (int l = 0; l < lr; l += 4) {
    vf4 w[8];
#pragma unroll
    for (int s8 = 0; s8 < 8; ++s8) w[s8] = *(const vf4*)&sc[s8 * 256 + l];
#pragma unroll
    for (int u = 0; u < 4; ++u) {
      vf4 pv = *(const vf4*)&post[(size_t)(l + u) * (BATCH * HID) + (size_t)b * HID + tid * 4];
#pragma unroll
      for (int s8 = 0; s8 < 8; ++s8) a[s8] = a[s8] + pv * w[s8][u];
    }
  }
#pragma unroll
  for (int s8 = 0; s8 < 8; ++s8) {
    vf4 r = a[s8] * stat[s8];
    *(vf4*)&out_hs[(size_t)(sbase + s8) * (BATCH * 2048) + (size_t)b * 2048 + 1024 + tid * 4] = r;
  }
}

// ---------------- host ----------------
extern "C" void kernel_launch(void* const* d_in, const int* in_sizes, int n_in,
                              void* d_out, int out_size, void* d_ws, size_t ws_size,
                              hipStream_t stream) {
  const float* incoming    = (const float*)d_in[0];
  const float* post        = (const float*)d_in[1];
  const float* h_init      = (const float*)d_in[2];
  const float* W_ih        = (const float*)d_in[3];
  const float* W_hh        = (const float*)d_in[4];
  const float* b_ih        = (const float*)d_in[5];
  const float* b_hh        = (const float*)d_in[6];
  const float* Wq          = (const float*)d_in[7];
  const float* bq          = (const float*)d_in[8];
  const int*   length      = (const int*)d_in[9];
  const int*   post_length = (const int*)d_in[10];
  float* out = (float*)d_out;
  float* ws  = (float*)d_ws;

  if (ws_size < WS_NEED) {
    fprintf(stderr, "[gru_attn] ERROR: ws too small (%zu < %zu)\n", ws_size, WS_NEED);
    return;
  }
  hipMemsetAsync(d_ws, 0, 4096, stream);  // barrier counters

  float* scr = ws + OFF_SCR;
  const int nci = SEQ / GI_CHUNK;  // 16
  for (int c = 0; c < nci; ++c) {
    hipLaunchKernelGGL(k_gi, dim3(24, GI_CHUNK), dim3(256), 0, stream,
                       incoming, W_ih, b_ih, scr, c * GI_CHUNK);
    hipLaunchKernelGGL(k_rec, dim3(256), dim3(256), 0, stream,
                       scr, W_hh, b_hh, length, h_init, out, ws, c * GI_CHUNK,
                       (c == nci - 1) ? 1 : 0);
  }
  const float* H = out + (size_t)BATCH * HID;
  const int ncq = SEQ / Q_CHUNK;  // 8
  for (int c = 0; c < ncq; ++c) {
    hipLaunchKernelGGL(k_q, dim3(8, 64), dim3(256), 0, stream,
                       H, Wq, bq, scr, c * Q_CHUNK);
    hipLaunchKernelGGL(k_attn, dim3(64, 4), dim3(256), 0, stream,
                       post, scr, post_length, out, c * Q_CHUNK);
  }
}